// Round 15
// baseline (116.665 us; speedup 1.0000x reference)
//
#include <hip/hip_runtime.h>
#include <stdint.h>

// Problem constants (fixed by setup_inputs)
#define NROWS 8192
#define DDIM 256
#define NJ2 32             // 256-col strips
#define STRIP_COLS 256
#define BN 32              // cols per t-iteration (2 phases x 16)
#define NTILES 8           // STRIP_COLS / BN
#define BM 128             // rows per block (4 waves x 32 rows)
#define NBLK 1056          // sum_{I=0..63} (32 - I/2) live triangular blocks
#define NSLOT 96           // 32 row-path (by J2) + 64 col-path (by I) slots

// Scores are computed directly in log2-units: e is scaled by sqrt(log2(e)/0.7)
// so acc = s*log2(e) and exp(s) == exp2(acc). Since s <= 1/0.7, exp2(acc) <= 4.17
// and per-row sums <= ~34k: no overflow, so NO log-sum-exp shift is needed at all.
#define ESCALE 1.4356159f        // sqrt(log2(e)/0.7)
#define LN2F   0.6931471806f
#define NEGBIG (-1e30f)

// Workspace layout (bytes): [0,256) accv; pm keys (uint, 96*8192); sums; ebfB.
#define WS_PMK   256
#define WS_NS    (WS_PMK + NSLOT * NROWS * 4)
#define WS_EBF   (WS_NS + NSLOT * NROWS * 4)
#define WS_ZERO16 ((WS_EBF) / 16)          // uint4 count to zero (accv + partials)

typedef __attribute__((ext_vector_type(8))) short short8;   // 8 bf16 = 4 VGPRs
typedef __attribute__((ext_vector_type(4))) float f32x4;    // MFMA 16x16 accumulator

__device__ __forceinline__ unsigned short f2bf(float x) {   // RNE float->bf16
  unsigned int u = __float_as_uint(x);
  u += 0x7fffu + ((u >> 16) & 1u);
  return (unsigned short)(u >> 16);
}

// Monotone float <-> uint key: a<b (non-NaN) <=> fkey(a)<fkey(b). Zero-init key
// (0x00000000) is below every real key -> "never written" sentinel.
__device__ __forceinline__ unsigned fkey(float f) {
  unsigned b = __float_as_uint(f);
  return (b & 0x80000000u) ? ~b : (b | 0x80000000u);
}
__device__ __forceinline__ float funkey(unsigned k) {
  unsigned b = (k & 0x80000000u) ? (k & 0x7fffffffu) : ~k;
  return __uint_as_float(b);
}

// ---------------- Kernel 1: row L2-normalize -> chunk-major bf16 (+zero partials) ----------------
// 2048 blocks x 256 threads = 524288 >= 393232 uint4 slots: each thread zeroes at
// most one uint4 of accv+partials (triangular slots are sparsely written -> the
// zero key/zero sum sentinel must pre-exist). ebfB: chunk (kc,row) at (kc*NROWS+row)*8.
__global__ __launch_bounds__(256) void knorm(const float* __restrict__ emb,
                                             unsigned short* __restrict__ ebfB,
                                             uint4* __restrict__ zbase) {
  const int zi = blockIdx.x * 256 + threadIdx.x;
  if (zi < WS_ZERO16) zbase[zi] = (uint4){0u, 0u, 0u, 0u};
  const int wave = threadIdx.x >> 6, lane = threadIdx.x & 63;
  const int row = blockIdx.x * 4 + wave;              // one wave per row
  const float4 v = *(const float4*)(emb + row * DDIM + lane * 4);
  float ss = v.x * v.x + v.y * v.y + v.z * v.z + v.w * v.w;
#pragma unroll
  for (int off = 1; off < 64; off <<= 1) ss += __shfl_xor(ss, off, 64);
  const float sc = rsqrtf(ss) * ESCALE;
  ushort4 o;
  o.x = f2bf(v.x * sc); o.y = f2bf(v.y * sc);
  o.z = f2bf(v.z * sc); o.w = f2bf(v.w * sc);
  // lane holds k = lane*4 .. lane*4+3 -> chunk kc = lane>>1, half (lane&1).
  *(ushort4*)(ebfB + ((lane >> 1) * NROWS + row) * 8 + (lane & 1) * 4) = o;
}

// ---------------- Kernel 2: symmetric, barrier-free, software-pipelined ----------------
// Combines the two independently-validated levers: (a) R14's per-wave ILP pipeline
// (named b0/b1 double buffer, loads issued a phase early, no LDS staging, no
// barriers in the K-loop) and (b) triangular symmetry (J2 >= I/2: 1056 blocks,
// half the MFMA/loads; epilogue also feeds a column path via quad shuffles into
// per-wave-PRIVATE LDS -- cross-wave combine happens once at kernel end behind the
// only __syncthreads in the kernel). R9's null result for symmetry was measured in
// the barrier-lockstep regime; the barrier-free pipeline makes block time scale
// with issued work. Slots: row path -> J2 (0..31); col path -> 32+I (32..95);
// unwritten slots keep the knorm-zeroed sentinel. No min-waves bound (R4 spill);
// no atomics/fences in the hot loop (R6).
__global__ __launch_bounds__(256) void kmain(const unsigned short* __restrict__ ebfB,
                                             const int* __restrict__ cats,
                                             unsigned* __restrict__ posPk,
                                             float* __restrict__ sumP) {
  // Decode (I, J2) from linear bid: per I there are 32 - (I>>1) strips (R9 decode).
  int bid = blockIdx.x, I = 0, base = 0;
  for (;; ++I) { const int c = NJ2 - (I >> 1); if (bid < base + c) break; base += c; }
  const int J2 = (I >> 1) + (bid - base);
  const int col0 = J2 * STRIP_COLS;
  const int t0 = (I * BM > col0) ? (NTILES / 2) : 0;  // odd-I boundary: skip 128 cols

  __shared__ float cpmL[4][STRIP_COLS], cnsL[4][STRIP_COLS];  // per-wave col partials, 8 KB
  const int tid = threadIdx.x;
  const int lane = tid & 63;
  const int lane15 = lane & 15, quad = lane >> 4;
  const int wave = tid >> 6;
  const int rowG = I * BM + wave * 32;                // this wave's 32 rows (m=2)

  // A fragments (chunk-major): a[m][kk] = rows rowG+m*16+lane15, k=kk*32+quad*8..+7.
  short8 a[2][8];
#pragma unroll
  for (int m = 0; m < 2; ++m)
#pragma unroll
    for (int kk = 0; kk < 8; ++kk)
      a[m][kk] = *(const short8*)(ebfB +
          ((size_t)(kk * 4 + quad) * NROWS + rowG + m * 16 + lane15) * 8);

  // Per-lane C-layout row categories: row = quad*4 + r (+ m*16)
  int cati[2][4];
#pragma unroll
  for (int m = 0; m < 2; ++m)
#pragma unroll
    for (int r = 0; r < 4; ++r)
      cati[m][r] = cats[rowG + m * 16 + quad * 4 + r];

  // Is this lane the diagonal element (row==col) within a diagonal 16x16 tile?
  bool dlr[4];
#pragma unroll
  for (int r = 0; r < 4; ++r) dlr[r] = (lane15 == quad * 4 + r);

  float pm[2][4], ns[2][4];
#pragma unroll
  for (int m = 0; m < 2; ++m)
#pragma unroll
    for (int r = 0; r < 4; ++r) { pm[m][r] = NEGBIG; ns[m][r] = 0.f; }

  // B-fragment base: chunk (kc = kk*4+quad, col = col0+lane15+off).
  const unsigned short* bbase = ebfB + ((size_t)quad * NROWS + col0 + lane15) * 8;

#define LOADB(buf, t, nt)                                                       \
  _Pragma("unroll")                                                             \
  for (int kk = 0; kk < 8; ++kk)                                                \
    buf[kk] = *(const short8*)(bbase +                                          \
        ((size_t)kk * 4 * NROWS + (t) * BN + (nt) * 16) * 8);

#define DOMFMA(buf, ACC0, ACC1)                                                 \
  f32x4 ACC0 = {0.f, 0.f, 0.f, 0.f}, ACC1 = {0.f, 0.f, 0.f, 0.f};              \
  _Pragma("unroll")                                                             \
  for (int kk = 0; kk < 8; ++kk) {                                              \
    ACC0 = __builtin_amdgcn_mfma_f32_16x16x32_bf16(a[0][kk], buf[kk], ACC0, 0, 0, 0); \
    ACC1 = __builtin_amdgcn_mfma_f32_16x16x32_bf16(a[1][kk], buf[kk], ACC1, 0, 0, 0); \
  }

  // Epilogue: row path (pm/ns) + col path (cpmv/cnsv by symmetry s_ij == s_ji).
  // Col partials: 2 quad shuffles then park in this wave's private LDS row -- no
  // cross-wave sync needed until the single end-of-kernel barrier.
#define EPI(ACC0, ACC1, t, nt)                                                  \
  {                                                                             \
    const int colBase = col0 + (t) * BN + (nt) * 16;                            \
    const int cj = cats[colBase + lane15];                                      \
    const bool dg0 = (rowG == colBase);                                         \
    const bool dg1 = (rowG + 16 == colBase);                                    \
    float cpmv = NEGBIG, cnsv = 0.f;                                            \
    _Pragma("unroll")                                                           \
    for (int m = 0; m < 2; ++m) {                                               \
      const bool dg = m ? dg1 : dg0;                                            \
      _Pragma("unroll")                                                         \
      for (int r = 0; r < 4; ++r) {                                             \
        const float s = m ? ACC1[r] : ACC0[r];      /* score in log2-units */   \
        const float e = __builtin_amdgcn_exp2f(s);                              \
        const bool same = (cj == cati[m][r]);                                   \
        float psv = same ? s : NEGBIG;                                          \
        if (dg) psv = dlr[r] ? NEGBIG : psv;        /* exclude self (rare) */   \
        pm[m][r] = fmaxf(pm[m][r], psv);                                        \
        const float ev = same ? 0.f : e;                                        \
        ns[m][r] += ev;                                                         \
        cpmv = fmaxf(cpmv, psv);                                                \
        cnsv += ev;                                                             \
      }                                                                         \
    }                                                                           \
    if ((colBase >> 7) > I) {              /* above-diagonal sub-block only */  \
      cpmv = fmaxf(cpmv, __shfl_xor(cpmv, 16, 64)); cnsv += __shfl_xor(cnsv, 16, 64); \
      cpmv = fmaxf(cpmv, __shfl_xor(cpmv, 32, 64)); cnsv += __shfl_xor(cnsv, 32, 64); \
      if (quad == 0) {                                                          \
        cpmL[wave][(t) * BN + (nt) * 16 + lane15] = cpmv;                       \
        cnsL[wave][(t) * BN + (nt) * 16 + lane15] = cnsv;                       \
      }                                                                         \
    }                                                                           \
  }

  short8 b0[8], b1[8];
  LOADB(b0, t0, 0);                        // prologue: first phase in flight

  for (int t = t0; t < NTILES; ++t) {
    LOADB(b1, t, 1);                       // issue nt=1 loads EARLY
    { DOMFMA(b0, acc0, acc1) EPI(acc0, acc1, t, 0) }   // cover for b1
    if (t + 1 < NTILES) LOADB(b0, t + 1, 0);           // issue next-t loads EARLY
    { DOMFMA(b1, acc2, acc3) EPI(acc2, acc3, t, 1) }   // cover for next b0
  }

  // Row path: reduce across the 16 lanes of each quad, store slot J2.
#pragma unroll
  for (int off = 1; off < 16; off <<= 1) {
#pragma unroll
    for (int m = 0; m < 2; ++m)
#pragma unroll
      for (int r = 0; r < 4; ++r) {
        pm[m][r] = fmaxf(pm[m][r], __shfl_xor(pm[m][r], off, 64));
        ns[m][r] += __shfl_xor(ns[m][r], off, 64);
      }
  }
  if (lane15 == 0) {
#pragma unroll
    for (int m = 0; m < 2; ++m)
#pragma unroll
      for (int r = 0; r < 4; ++r) {
        const int row = rowG + m * 16 + quad * 4 + r;
        posPk[J2 * NROWS + row] = fkey(pm[m][r]);
        sumP [J2 * NROWS + row] = ns[m][r];
      }
  }

  // Col path: single barrier, cross-wave combine, store slot 32+I. Thread c owns
  // strip col c; active iff col0+c >= (I+1)*128 (written by every wave for all
  // its live phases covering that col).
  __syncthreads();
  const int cs = (I + 1) * BM - col0;      // cs in {<=0, 128, 256}
  const int c = tid;
  if (c >= cs) {
    const float p = fmaxf(fmaxf(cpmL[0][c], cpmL[1][c]),
                          fmaxf(cpmL[2][c], cpmL[3][c]));
    const float n = cnsL[0][c] + cnsL[1][c] + cnsL[2][c] + cnsL[3][c];
    posPk[(NJ2 + I) * NROWS + col0 + c] = fkey(p);
    sumP [(NJ2 + I) * NROWS + col0 + c] = n;
  }
}

// ---------------- Kernel 3: merge 96 slots, per-row loss, reduce, finalize ----------------
__global__ __launch_bounds__(256) void kmerge(const unsigned* __restrict__ posPk,
                                              const float* __restrict__ sumP,
                                              float* __restrict__ acc,
                                              float* __restrict__ out) {
  const int row = blockIdx.x * 256 + threadIdx.x;
  unsigned kmax = 0u; float ns = 0.f;
#pragma unroll 8
  for (int s = 0; s < NSLOT; ++s) {
    kmax = max(kmax, posPk[s * NROWS + row]);   // key 0 = never written
    ns += sumP[s * NROWS + row];
  }
  const float pm = funkey(kmax);
  const bool valid = (pm > -1e29f) && (ns > 0.f);
  // pm is pos*log2(e); loss = -pos + ln(exp2(pm) + sum_neg exp(s))   (no shift needed)
  float loss = valid ? (logf(__builtin_amdgcn_exp2f(pm) + ns) - pm * LN2F) : 0.f;
  float cnt = valid ? 1.f : 0.f;
#pragma unroll
  for (int off = 1; off < 64; off <<= 1) {
    loss += __shfl_xor(loss, off, 64);
    cnt += __shfl_xor(cnt, off, 64);
  }
  if ((threadIdx.x & 63) == 0) {
    atomicAdd(&acc[0], loss);
    atomicAdd(&acc[1], cnt);
    __threadfence();                       // my adds visible before the counter bump
  }
  __syncthreads();
  if (threadIdx.x == 0) {
    const int prev = atomicAdd((int*)(acc + 2), 1);
    if (prev == (int)gridDim.x - 1) {      // last block finalizes
      const float L = atomicAdd(&acc[0], 0.f);   // coherent reads
      const float C = atomicAdd(&acc[1], 0.f);
      out[0] = L / fmaxf(C, 1.f);
    }
  }
}

// ---------------- Launch ----------------
extern "C" void kernel_launch(void* const* d_in, const int* in_sizes, int n_in,
                              void* d_out, int out_size, void* d_ws, size_t ws_size,
                              hipStream_t stream) {
  const float* emb = (const float*)d_in[0];
  const int* cats = (const int*)d_in[1];
  // d_in[2] (font_labels) is unused by the reference.
  float* out = (float*)d_out;

  char* ws = (char*)d_ws;
  float* accv = (float*)ws;                                  // loss, cnt, block counter
  unsigned* posPk = (unsigned*)(ws + WS_PMK);                // 96 slots x 8192 keys
  float* sumP = (float*)(ws + WS_NS);                        // 96 slots x 8192 sums
  unsigned short* ebfB = (unsigned short*)(ws + WS_EBF);     // 4 MB chunk-major bf16

  knorm<<<NROWS / 4, 256, 0, stream>>>(emb, ebfB, (uint4*)ws);
  kmain<<<NBLK, 256, 0, stream>>>(ebfB, cats, posPk, sumP);
  kmerge<<<NROWS / 256, 256, 0, stream>>>(posPk, sumP, accv, out);
}